// Round 10
// baseline (46.177 us; speedup 1.0000x reference)
//
#include <hip/hip_runtime.h>

#define NB 16
#define NN 256
#define NH 128
#define NE 16

typedef float v4f  __attribute__((ext_vector_type(4)));
typedef short bf16x8 __attribute__((ext_vector_type(8)));
typedef unsigned int uint;

constexpr long long EF_ELEMS = (long long)NB * NN * NN * NE; // 16777216

// ws layout (floats): bps[16] | albe[1280] | Pi[4096*32] | Pj[4096*32]

// ==================== A: fused prep (block 2048) + proj (blocks 0..2047) ============
__global__ __launch_bounds__(256) void k_prep_proj2(
    const float* __restrict__ node, const float* __restrict__ uW1,
    const float* __restrict__ dW1, const float* __restrict__ db1,
    const float* __restrict__ dW2, const float* __restrict__ db2,
    const float* __restrict__ ub1,
    float* __restrict__ bps, float* __restrict__ albe,
    float* __restrict__ Pi, float* __restrict__ Pj)
{
    const int t = threadIdx.x;
    if (blockIdx.x == 2048) {
        // ---- prep: piecewise-linear fold of dist MLP into (alpha,beta) per segment
        __shared__ float sM[512];      // M[16][32] = dW2 @ uW1[256:,:]
        __shared__ float sBp[16];
        __shared__ float sA[16], sB[16];
        for (int i = t; i < 512; i += 256) {
            const int k = i >> 5, c = i & 31;
            float s = 0.f;
#pragma unroll
            for (int e = 0; e < 16; ++e)
                s = fmaf(dW2[k * 16 + e], uW1[(256 + e) * 32 + c], s);
            sM[i] = s;
        }
        if (t < 16) { sA[t] = dW1[t]; sB[t] = db1[t]; }
        __syncthreads();
        if (t < 16) {
            const float a = sA[t];
            const float x = (a != 0.f) ? (-sB[t] / a) : -1e30f;
            int r = 0;
            for (int q = 0; q < 16; ++q) {
                const float aq = sA[q];
                const float xq = (aq != 0.f) ? (-sB[q] / aq) : -1e30f;
                r += (xq < x) || (xq == x && q < t);
            }
            sBp[r] = x;
        }
        __syncthreads();
        if (t < 16) bps[t] = sBp[t];
        for (int i = t; i < 544; i += 256) {
            const int s = i >> 5, c = i & 31;
            float dt;
            if (s == 0)       dt = sBp[0] - 1.0f;
            else if (s == 16) dt = sBp[15] + 1.0f;
            else              dt = 0.5f * (sBp[s - 1] + sBp[s]);
            float alpha = 0.f, beta = 0.f;
#pragma unroll
            for (int k = 0; k < 16; ++k) {
                if (fmaf(sA[k], dt, sB[k]) > 0.f) {
                    const float m = sM[k * 32 + c];
                    alpha = fmaf(sA[k], m, alpha);
                    beta  = fmaf(sB[k], m, beta);
                }
            }
            float c2 = ub1[c];
#pragma unroll
            for (int e = 0; e < 16; ++e)
                c2 = fmaf(db2[e], uW1[(256 + e) * 32 + c], c2);
            albe[s * 68 + c]      = alpha;
            albe[s * 68 + 32 + c] = beta + c2;
        }
        for (int i = 1156 + t; i < 1280; i += 256) albe[i] = 0.f;  // pad for vec copy
    } else {
        // ---- proj: 2 rows/block, k-split x2 -> 64-FMA chains, shfl reduce
        const int r    = t >> 7;          // row within block
        const int half = (t >> 6) & 1;    // 0 -> Pi, 1 -> Pj
        const int ks   = (t >> 5) & 1;    // k-split
        const int c    = t & 31;
        const int row  = blockIdx.x * 2 + r;
        __shared__ float nrow[2][128];
        nrow[r][t & 127] = node[(size_t)row * 128 + (t & 127)];
        __syncthreads();
        const float* w = uW1 + half * 128 * 32 + c;
        const int k0 = ks * 64;
        float s = 0.f;
#pragma unroll 8
        for (int k = 0; k < 64; ++k)
            s = fmaf(nrow[r][k0 + k], w[(size_t)(k0 + k) * 32], s);
        s += __shfl_xor(s, 32);           // combine the two k-halves (lane^32 flips ks)
        if (!(t & 32))
            (half ? Pj : Pi)[(size_t)row * 32 + c] = s;
    }
}

// ==================== B: edge, 4-lanes-per-edge, register-resident B-frag ============
// Wave wv owns edges [wv*64, wv*64+64) of each row, processed in 4 passes of 16.
// In pass p, lane (eRow = lane&15, g = lane>>4) computes channels [8g, 8g+8) of edge
// p*16+eRow. The B-fragment dword m = pack(h[2(4g+m)], h[2(4g+m)+1]) is then built
// IN REGISTERS with the same cvt_pk pairing as the verified LDS-staged layout --
// identical MFMA semantics, no LDS round-trip, no lgkmcnt serialization. The 4
// passes are independent -> ILP. LN uses one-pass E[x^2]-mu^2 + 2 shfl_xor levels.
__global__ __launch_bounds__(256) void k_edge8(
    const float* __restrict__ dist, const int* __restrict__ visited,
    const float* __restrict__ ln_g, const float* __restrict__ ln_b,
    const float* __restrict__ uW2, const float* __restrict__ ub2,
    const float* __restrict__ bps, const float* __restrict__ albe_g,
    const float* __restrict__ Pi, const float* __restrict__ Pj,
    const float* __restrict__ nW1, const float* __restrict__ nb1,
    const float* __restrict__ nW2, const float* __restrict__ nb2,
    float* __restrict__ ef_out, float* __restrict__ msg_out)
{
    const int row0 = blockIdx.x * 2;      // 2 rows, same batch b
    const int b = row0 >> 8;
    const int j = threadIdx.x;

    __shared__ float albe_s[1280];        // 5120 B (68-float seg stride)
    __shared__ float red2[2][4][16];      // 512 B
    __shared__ float pool_s[2][16];       // 128 B
    __shared__ float hid_s[2][64];        // 512 B
    // total ~6.3 KB -> LDS no longer caps occupancy

    // stage albe (320 float4, 2 rounds)
    {
        const float4* ag = reinterpret_cast<const float4*>(albe_g);
        float4* as = reinterpret_cast<float4*>(albe_s);
        for (int q = j; q < 320; q += 256) as[q] = ag[q];
    }

    const int lane = j & 63, wv = j >> 6;
    const int eRow = lane & 15;           // edge-in-tile / B col / D col
    const int g    = lane >> 4;           // channel group (8 ch) / k-group

    // per-lane LN affine params for channels [8g, 8g+8)
    float gl[8], bl[8];
    {
        const float4 g0 = *reinterpret_cast<const float4*>(&ln_g[g * 8]);
        const float4 g1 = *reinterpret_cast<const float4*>(&ln_g[g * 8 + 4]);
        const float4 b0 = *reinterpret_cast<const float4*>(&ln_b[g * 8]);
        const float4 b1 = *reinterpret_cast<const float4*>(&ln_b[g * 8 + 4]);
        gl[0]=g0.x; gl[1]=g0.y; gl[2]=g0.z; gl[3]=g0.w;
        gl[4]=g1.x; gl[5]=g1.y; gl[6]=g1.z; gl[7]=g1.w;
        bl[0]=b0.x; bl[1]=b0.y; bl[2]=b0.z; bl[3]=b0.w;
        bl[4]=b1.x; bl[5]=b1.y; bl[6]=b1.z; bl[7]=b1.w;
    }

    // A-fragments (uW2^T, bf16 hi/lo split) in registers; same cvt_pk order as the
    // verified layout, so MFMA K-pairing is unchanged.
    bf16x8 ahi, alo;
    {
        union { uint u[4]; bf16x8 v; } Uhi, Ulo;
#pragma unroll
        for (int p = 0; p < 4; ++p) {
            const int q = g * 4 + p;
            const float w0 = uW2[(2 * q) * 16 + eRow];
            const float w1 = uW2[(2 * q + 1) * 16 + eRow];
            uint W00, W11, Whi, Wlo;
            asm("v_cvt_pk_bf16_f32 %0, %1, %2" : "=v"(W00) : "v"(w0), "v"(w0));
            asm("v_cvt_pk_bf16_f32 %0, %1, %2" : "=v"(W11) : "v"(w1), "v"(w1));
            const float w0h = __uint_as_float(W00 << 16);
            const float w1h = __uint_as_float(W11 << 16);
            asm("v_cvt_pk_bf16_f32 %0, %1, %2" : "=v"(Whi) : "v"(w0), "v"(w1));
            asm("v_cvt_pk_bf16_f32 %0, %1, %2" : "=v"(Wlo) : "v"(w0 - w0h), "v"(w1 - w1h));
            Uhi.u[p] = Whi;
            Ulo.u[p] = Wlo;
        }
        ahi = Uhi.v;
        alo = Ulo.v;
    }

    // per-thread d + segment for OLD edge mapping (thread j <-> edge wv*64+lane);
    // redistributed per pass by one shfl each.
    float dq[2];
    int   sq[2];
#pragma unroll
    for (int r = 0; r < 2; ++r) {
        dq[r] = dist[(size_t)(row0 + r) * NN + j];
        int seg = 0;
#pragma unroll
        for (int k = 0; k < 16; ++k) seg += (dq[r] > bps[k]) ? 1 : 0;
        sq[r] = seg;
    }

    float scv[2];
#pragma unroll
    for (int r = 0; r < 2; ++r) scv[r] = visited[row0 + r] ? 0.5f : 1.0f;

    const float4 ub2v = *reinterpret_cast<const float4*>(&ub2[g * 4]);

    __syncthreads();   // albe_s ready

#pragma unroll
    for (int r = 0; r < 2; ++r) {
        const int row = row0 + r;
        const float scale = scv[r];

        // Pi channels [8g, 8g+8) for this row (broadcast, 4 addrs/wave)
        const float4 pi0 = *reinterpret_cast<const float4*>(Pi + (size_t)row * 32 + g * 8);
        const float4 pi1 = *reinterpret_cast<const float4*>(Pi + (size_t)row * 32 + g * 8 + 4);
        const float piv[8] = {pi0.x, pi0.y, pi0.z, pi0.w, pi1.x, pi1.y, pi1.z, pi1.w};

        v4f accsum = {0.f, 0.f, 0.f, 0.f};
#pragma unroll
        for (int p = 0; p < 4; ++p) {
            const int edge = wv * 64 + p * 16 + eRow;

            // redistribute d and seg of this pass's edge to its 4 lanes
            const float dsw = __shfl(dq[r], p * 16 + eRow);
            const int   ssw = __shfl(sq[r], p * 16 + eRow);

            // albe gather: channels [8g, 8g+8) of segment ssw (seg-stride 68 ->
            // ~2-3-way bank aliasing, free-ish per m136)
            const float* ab = &albe_s[ssw * 68 + g * 8];
            const float4 al0 = *reinterpret_cast<const float4*>(&ab[0]);
            const float4 al1 = *reinterpret_cast<const float4*>(&ab[4]);
            const float4 be0 = *reinterpret_cast<const float4*>(&ab[32]);
            const float4 be1 = *reinterpret_cast<const float4*>(&ab[36]);

            // Pj channels [8g, 8g+8) of this edge (L1/L2-hot panel)
            const float* pjp = Pj + ((size_t)(b * NN) + edge) * 32 + g * 8;
            const float4 pj0 = *reinterpret_cast<const float4*>(pjp);
            const float4 pj1 = *reinterpret_cast<const float4*>(pjp + 4);

            float pre[8];
            pre[0] = piv[0] + pj0.x + fmaf(dsw, al0.x, be0.x);
            pre[1] = piv[1] + pj0.y + fmaf(dsw, al0.y, be0.y);
            pre[2] = piv[2] + pj0.z + fmaf(dsw, al0.z, be0.z);
            pre[3] = piv[3] + pj0.w + fmaf(dsw, al0.w, be0.w);
            pre[4] = piv[4] + pj1.x + fmaf(dsw, al1.x, be1.x);
            pre[5] = piv[5] + pj1.y + fmaf(dsw, al1.y, be1.y);
            pre[6] = piv[6] + pj1.z + fmaf(dsw, al1.z, be1.z);
            pre[7] = piv[7] + pj1.w + fmaf(dsw, al1.w, be1.w);

            // one-pass LN partials over 8 local channels
            float s  = ((pre[0] + pre[1]) + (pre[2] + pre[3]))
                     + ((pre[4] + pre[5]) + (pre[6] + pre[7]));
            float qq = fmaf(pre[0], pre[0], fmaf(pre[1], pre[1],
                       fmaf(pre[2], pre[2], pre[3] * pre[3])))
                     + fmaf(pre[4], pre[4], fmaf(pre[5], pre[5],
                       fmaf(pre[6], pre[6], pre[7] * pre[7])));
            // combine over the 4 g-lanes of this edge (lanes e, e+16, e+32, e+48)
            s  += __shfl_xor(s, 16);  s  += __shfl_xor(s, 32);
            qq += __shfl_xor(qq, 16); qq += __shfl_xor(qq, 32);
            const float mu   = s * (1.f / 32.f);
            const float var  = fmaf(-mu, mu, qq * (1.f / 32.f));
            const float rstd = rsqrtf(fmaxf(var, 0.f) + 1e-5f);

            // h = relu(LN affine) for the 8 local channels; pack B-frag in regs
            union { uint u[4]; bf16x8 v; } Bf;
#pragma unroll
            for (int m = 0; m < 4; ++m) {
                const float h0 = fmaxf(fmaf((pre[2*m]   - mu) * rstd, gl[2*m],   bl[2*m]),   0.f);
                const float h1 = fmaxf(fmaf((pre[2*m+1] - mu) * rstd, gl[2*m+1], bl[2*m+1]), 0.f);
                uint rr;
                asm("v_cvt_pk_bf16_f32 %0, %1, %2" : "=v"(rr) : "v"(h0), "v"(h1));
                Bf.u[m] = rr;
            }

            v4f acc = {ub2v.x, ub2v.y, ub2v.z, ub2v.w};
            acc = __builtin_amdgcn_mfma_f32_16x16x32_bf16(alo, Bf.v, acc, 0, 0, 0);
            acc = __builtin_amdgcn_mfma_f32_16x16x32_bf16(ahi, Bf.v, acc, 0, 0, 0);
            acc[0] *= scale; acc[1] *= scale; acc[2] *= scale; acc[3] *= scale;
            // D: col=lane&15 -> edge, row = g*4+reg -> e; 1KB contiguous per wave-store
            *reinterpret_cast<v4f*>(ef_out + ((size_t)row * NN + edge) * 16 + g * 4) = acc;
            accsum += acc;
        }

        // pooled partial: sum over this wave's 64 edges (reduce across e-lanes)
#pragma unroll
        for (int rr = 0; rr < 4; ++rr) {
            float v = accsum[rr];
            v += __shfl_xor(v, 1);
            v += __shfl_xor(v, 2);
            v += __shfl_xor(v, 4);
            v += __shfl_xor(v, 8);
            accsum[rr] = v;
        }
        if (eRow == 0)
            *reinterpret_cast<v4f*>(&red2[r][wv][g * 4]) = accsum;
    }

    __syncthreads();   // red2 complete

    // pooled means (2 rows x 16 e)
    if (j < 32) {
        const int r = j >> 4, e = j & 15;
        pool_s[r][e] = (red2[r][0][e] + red2[r][1][e] + red2[r][2][e] + red2[r][3][e])
                       * (1.f / 256.f);
    }
    __syncthreads();

    // node MLP layer 1
    if (j < 128) {
        const int r = j >> 6, u = j & 63;
        float s = nb1[u];
#pragma unroll
        for (int e = 0; e < 16; ++e)
            s = fmaf(pool_s[r][e], nW1[e * 64 + u], s);
        hid_s[r][u] = fmaxf(s, 0.f);
    }
    __syncthreads();

    // node MLP layer 2 (2x128 = 256 outputs)
    {
        const int r = j >> 7, o = j & 127;
        float s = nb2[o];
#pragma unroll 8
        for (int q = 0; q < 64; ++q)
            s = fmaf(hid_s[r][q], nW2[q * 128 + o], s);
        msg_out[(size_t)(row0 + r) * 128 + o] = s;
    }
}

extern "C" void kernel_launch(void* const* d_in, const int* in_sizes, int n_in,
                              void* d_out, int out_size, void* d_ws, size_t ws_size,
                              hipStream_t stream)
{
    const float* node    = (const float*)d_in[0];
    const float* dist    = (const float*)d_in[1];
    const int*   visited = (const int*)  d_in[2];
    const float* dW1     = (const float*)d_in[3];
    const float* db1     = (const float*)d_in[4];
    const float* dW2     = (const float*)d_in[5];
    const float* db2     = (const float*)d_in[6];
    const float* uW1     = (const float*)d_in[7];
    const float* ub1     = (const float*)d_in[8];
    const float* ln_g    = (const float*)d_in[9];
    const float* ln_b    = (const float*)d_in[10];
    const float* uW2     = (const float*)d_in[11];
    const float* ub2     = (const float*)d_in[12];
    const float* nW1     = (const float*)d_in[13];
    const float* nb1     = (const float*)d_in[14];
    const float* nW2     = (const float*)d_in[15];
    const float* nb2     = (const float*)d_in[16];

    float* ws   = (float*)d_ws;
    float* bps  = ws;                    // 16
    float* albe = ws + 16;               // 1280 (1156 used + pad)
    float* Pi   = ws + 16 + 1280;        // 4096*32
    float* Pj   = Pi + 4096 * 32;        // 4096*32

    float* out = (float*)d_out;
    float* msg = out + EF_ELEMS;

    hipLaunchKernelGGL(k_prep_proj2, dim3(2049), dim3(256), 0, stream,
                       node, uW1, dW1, db1, dW2, db2, ub1, bps, albe, Pi, Pj);
    hipLaunchKernelGGL(k_edge8, dim3(2048), dim3(256), 0, stream,
                       dist, visited, ln_g, ln_b, uW2, ub2, bps, albe, Pi, Pj,
                       nW1, nb1, nW2, nb2, out, msg);
}

// Round 11
// 42.524 us; speedup vs baseline: 1.0859x; 1.0859x over previous
//
#include <hip/hip_runtime.h>

#define NB 16
#define NN 256
#define NH 128
#define NE 16

typedef float v4f  __attribute__((ext_vector_type(4)));
typedef short bf16x8 __attribute__((ext_vector_type(8)));
typedef unsigned int uint;

constexpr long long EF_ELEMS = (long long)NB * NN * NN * NE; // 16777216

// ws layout (floats): bps[16] | albe[1280] | Pi[4096*32] | Pj[4096*32]

// ==================== A: fused prep (block 2048) + proj (blocks 0..2047) ============
__global__ __launch_bounds__(256) void k_prep_proj2(
    const float* __restrict__ node, const float* __restrict__ uW1,
    const float* __restrict__ dW1, const float* __restrict__ db1,
    const float* __restrict__ dW2, const float* __restrict__ db2,
    const float* __restrict__ ub1,
    float* __restrict__ bps, float* __restrict__ albe,
    float* __restrict__ Pi, float* __restrict__ Pj)
{
    const int t = threadIdx.x;
    if (blockIdx.x == 2048) {
        // ---- prep: piecewise-linear fold of dist MLP into (alpha,beta) per segment
        __shared__ float sM[512];      // M[16][32] = dW2 @ uW1[256:,:]
        __shared__ float sBp[16];
        __shared__ float sA[16], sB[16];
        for (int i = t; i < 512; i += 256) {
            const int k = i >> 5, c = i & 31;
            float s = 0.f;
#pragma unroll
            for (int e = 0; e < 16; ++e)
                s = fmaf(dW2[k * 16 + e], uW1[(256 + e) * 32 + c], s);
            sM[i] = s;
        }
        if (t < 16) { sA[t] = dW1[t]; sB[t] = db1[t]; }
        __syncthreads();
        if (t < 16) {
            const float a = sA[t];
            const float x = (a != 0.f) ? (-sB[t] / a) : -1e30f;
            int r = 0;
            for (int q = 0; q < 16; ++q) {
                const float aq = sA[q];
                const float xq = (aq != 0.f) ? (-sB[q] / aq) : -1e30f;
                r += (xq < x) || (xq == x && q < t);
            }
            sBp[r] = x;
        }
        __syncthreads();
        if (t < 16) bps[t] = sBp[t];
        for (int i = t; i < 544; i += 256) {
            const int s = i >> 5, c = i & 31;
            float dt;
            if (s == 0)       dt = sBp[0] - 1.0f;
            else if (s == 16) dt = sBp[15] + 1.0f;
            else              dt = 0.5f * (sBp[s - 1] + sBp[s]);
            float alpha = 0.f, beta = 0.f;
#pragma unroll
            for (int k = 0; k < 16; ++k) {
                if (fmaf(sA[k], dt, sB[k]) > 0.f) {
                    const float m = sM[k * 32 + c];
                    alpha = fmaf(sA[k], m, alpha);
                    beta  = fmaf(sB[k], m, beta);
                }
            }
            float c2 = ub1[c];
#pragma unroll
            for (int e = 0; e < 16; ++e)
                c2 = fmaf(db2[e], uW1[(256 + e) * 32 + c], c2);
            albe[s * 68 + c]      = alpha;
            albe[s * 68 + 32 + c] = beta + c2;
        }
        for (int i = 1156 + t; i < 1280; i += 256) albe[i] = 0.f;  // pad for vec copy
    } else {
        // ---- proj: 2 rows/block, k-split x2 -> 64-FMA chains, shfl reduce
        const int r    = t >> 7;          // row within block
        const int half = (t >> 6) & 1;    // 0 -> Pi, 1 -> Pj
        const int ks   = (t >> 5) & 1;    // k-split
        const int c    = t & 31;
        const int row  = blockIdx.x * 2 + r;
        __shared__ float nrow[2][128];
        nrow[r][t & 127] = node[(size_t)row * 128 + (t & 127)];
        __syncthreads();
        const float* w = uW1 + half * 128 * 32 + c;
        const int k0 = ks * 64;
        float s = 0.f;
#pragma unroll 8
        for (int k = 0; k < 64; ++k)
            s = fmaf(nrow[r][k0 + k], w[(size_t)(k0 + k) * 32], s);
        s += __shfl_xor(s, 32);           // combine the two k-halves (lane^32 flips ks)
        if (!(t & 32))
            (half ? Pj : Pi)[(size_t)row * 32 + c] = s;
    }
}

// ==================== B: edge, 8 rows/block via 2x 4-wave groups ====================
// 512 threads = 2 groups x 4 waves. Group grp runs the proven R6 4-row body on rows
// row0 + grp*4 .. +3. Prologue (albe stage, A-frag build, Pj loads) paid ONCE per
// block for 8 rows. h_lds is per-group; within a group it is wave-private (each wave
// reads only the 64 edge-rows it wrote), so no barrier inside the row loop.
__global__ __launch_bounds__(512, 4) void k_edge9(
    const float* __restrict__ dist, const int* __restrict__ visited,
    const float* __restrict__ ln_g, const float* __restrict__ ln_b,
    const float* __restrict__ uW2, const float* __restrict__ ub2,
    const float* __restrict__ bps, const float* __restrict__ albe_g,
    const float* __restrict__ Pi, const float* __restrict__ Pj,
    const float* __restrict__ nW1, const float* __restrict__ nb1,
    const float* __restrict__ nW2, const float* __restrict__ nb2,
    float* __restrict__ ef_out, float* __restrict__ msg_out)
{
    const int row0 = blockIdx.x * 8;      // 8 rows, all in batch b (256 % 8 == 0)
    const int b = row0 >> 8;
    const int j = threadIdx.x;            // 0..511
    const int grp = j >> 8;               // group 0/1 -> rows row0+grp*4 ..
    const int jj = j & 255;               // index within group

    __shared__ float albe_s[1280];        // 5120 B
    __shared__ uint  h_lds[2][256 * 20];  // 40960 B (stride 20: 2-way b128 = free)
    __shared__ float red2[8][4][16];      // 2048 B [row][wave][e]
    __shared__ float pool_s[8][16];       // 512 B
    __shared__ float hid_s[8][64];        // 2048 B
    // total ~50.7 KB -> 3 blocks/CU capacity (need 2)

    // stage albe once per block (320 float4)
    {
        const float4* ag = reinterpret_cast<const float4*>(albe_g);
        float4* as = reinterpret_cast<float4*>(albe_s);
        for (int q = j; q < 320; q += 512) as[q] = ag[q];
    }

    const int lane = jj & 63, wv = jj >> 6;
    const int eRow = lane & 15;           // A row (e) / B col (edge-in-tile)
    const int g    = lane >> 4;           // k-group

    // A-fragments (uW2^T, bf16 hi/lo split) in registers; same cvt_pk order as the
    // verified layout, so MFMA K-pairing is unchanged.
    bf16x8 ahi, alo;
    {
        union { uint u[4]; bf16x8 v; } Uhi, Ulo;
#pragma unroll
        for (int p = 0; p < 4; ++p) {
            const int q = g * 4 + p;
            const float w0 = uW2[(2 * q) * 16 + eRow];
            const float w1 = uW2[(2 * q + 1) * 16 + eRow];
            uint W00, W11, Whi, Wlo;
            asm("v_cvt_pk_bf16_f32 %0, %1, %2" : "=v"(W00) : "v"(w0), "v"(w0));
            asm("v_cvt_pk_bf16_f32 %0, %1, %2" : "=v"(W11) : "v"(w1), "v"(w1));
            const float w0h = __uint_as_float(W00 << 16);
            const float w1h = __uint_as_float(W11 << 16);
            asm("v_cvt_pk_bf16_f32 %0, %1, %2" : "=v"(Whi) : "v"(w0), "v"(w1));
            asm("v_cvt_pk_bf16_f32 %0, %1, %2" : "=v"(Wlo) : "v"(w0 - w0h), "v"(w1 - w1h));
            Uhi.u[p] = Whi;
            Ulo.u[p] = Wlo;
        }
        ahi = Uhi.v;
        alo = Ulo.v;
    }

    // preload this group's 4 dists (coalesced per row)
    const int rbase = row0 + grp * 4;
    float dq[4];
#pragma unroll
    for (int r = 0; r < 4; ++r)
        dq[r] = dist[(size_t)(rbase + r) * NN + jj];

    const float4 ub2v = *reinterpret_cast<const float4*>(&ub2[g * 4]);
    const float4* pj4 = reinterpret_cast<const float4*>(Pj + ((size_t)(b * NN + jj)) * 32);
    float4 pj[8];
#pragma unroll
    for (int q = 0; q < 8; ++q) pj[q] = pj4[q];

    __syncthreads();   // albe_s ready

#pragma unroll
    for (int r = 0; r < 4; ++r) {
        const int row = rbase + r;
        const float d = dq[r];

        // segment lookup
        int seg = 0;
#pragma unroll
        for (int k = 0; k < 16; ++k) seg += (d > bps[k]) ? 1 : 0;
        const float* ab = &albe_s[seg * 68];

        // pre[c] = Pi[row][c] + Pj[b,jj][c] + d*alpha[c] + beta[c]
        const float* PiRow = Pi + (size_t)row * 32;   // uniform -> s_load
        float pre[32];
#pragma unroll
        for (int q = 0; q < 8; ++q) {
            const float4 al = *reinterpret_cast<const float4*>(&ab[q * 4]);
            const float4 be = *reinterpret_cast<const float4*>(&ab[32 + q * 4]);
            pre[q * 4 + 0] = PiRow[q * 4 + 0] + pj[q].x + fmaf(d, al.x, be.x);
            pre[q * 4 + 1] = PiRow[q * 4 + 1] + pj[q].y + fmaf(d, al.y, be.y);
            pre[q * 4 + 2] = PiRow[q * 4 + 2] + pj[q].z + fmaf(d, al.z, be.z);
            pre[q * 4 + 3] = PiRow[q * 4 + 3] + pj[q].w + fmaf(d, al.w, be.w);
        }

        // LayerNorm over 32 channels
        float s0 = 0.f, s1 = 0.f, s2 = 0.f, s3 = 0.f;
#pragma unroll
        for (int c = 0; c < 32; c += 4) { s0 += pre[c]; s1 += pre[c+1]; s2 += pre[c+2]; s3 += pre[c+3]; }
        const float mu = ((s0 + s1) + (s2 + s3)) * (1.f / 32.f);
        float v0 = 0.f, v1 = 0.f, v2 = 0.f, v3 = 0.f;
#pragma unroll
        for (int c = 0; c < 32; c += 4) {
            pre[c]   -= mu; v0 = fmaf(pre[c],   pre[c],   v0);
            pre[c+1] -= mu; v1 = fmaf(pre[c+1], pre[c+1], v1);
            pre[c+2] -= mu; v2 = fmaf(pre[c+2], pre[c+2], v2);
            pre[c+3] -= mu; v3 = fmaf(pre[c+3], pre[c+3], v3);
        }
        const float rstd = rsqrtf(fmaf((v0 + v1) + (v2 + v3), 1.f / 32.f, 1e-5f));

        // h = relu(LN affine); pack to bf16 pairs -> LDS row jj
#pragma unroll
        for (int c = 0; c < 32; ++c)
            pre[c] = fmaxf(fmaf(pre[c] * rstd, ln_g[c], ln_b[c]), 0.f);
        {
            uint hw[16];
#pragma unroll
            for (int q = 0; q < 16; ++q) {
                uint rr;
                asm("v_cvt_pk_bf16_f32 %0, %1, %2" : "=v"(rr) : "v"(pre[2*q]), "v"(pre[2*q+1]));
                hw[q] = rr;
            }
            uint* hrow = &h_lds[grp][jj * 20];
            *reinterpret_cast<uint4*>(hrow + 0)  = make_uint4(hw[0],  hw[1],  hw[2],  hw[3]);
            *reinterpret_cast<uint4*>(hrow + 4)  = make_uint4(hw[4],  hw[5],  hw[6],  hw[7]);
            *reinterpret_cast<uint4*>(hrow + 8)  = make_uint4(hw[8],  hw[9],  hw[10], hw[11]);
            *reinterpret_cast<uint4*>(hrow + 12) = make_uint4(hw[12], hw[13], hw[14], hw[15]);
        }
        // h_lds[grp] is wave-private; same-wave DS program order makes write->read safe.

        const float scale = visited[row] ? 0.5f : 1.0f;   // uniform
        v4f accsum = {0.f, 0.f, 0.f, 0.f};
#pragma unroll
        for (int t = 0; t < 4; ++t) {
            const int edge = wv * 64 + t * 16 + eRow;
            const bf16x8 bfr = *reinterpret_cast<const bf16x8*>(&h_lds[grp][edge * 20 + g * 4]);
            v4f acc = {ub2v.x, ub2v.y, ub2v.z, ub2v.w};
            acc = __builtin_amdgcn_mfma_f32_16x16x32_bf16(alo, bfr, acc, 0, 0, 0);
            acc = __builtin_amdgcn_mfma_f32_16x16x32_bf16(ahi, bfr, acc, 0, 0, 0);
            acc[0] *= scale; acc[1] *= scale; acc[2] *= scale; acc[3] *= scale;
            *reinterpret_cast<v4f*>(ef_out + ((size_t)row * NN + edge) * 16 + g * 4) = acc;
            accsum += acc;
        }
#pragma unroll
        for (int rr = 0; rr < 4; ++rr) {
            float v = accsum[rr];
            v += __shfl_xor(v, 1);
            v += __shfl_xor(v, 2);
            v += __shfl_xor(v, 4);
            v += __shfl_xor(v, 8);
            accsum[rr] = v;
        }
        if (eRow == 0)
            *reinterpret_cast<v4f*>(&red2[grp * 4 + r][wv][g * 4]) = accsum;
    }

    __syncthreads();   // red2 complete for all 8 rows

    // pooled means (8 rows x 16 e = 128 threads)
    if (j < 128) {
        const int r = j >> 4, e = j & 15;
        pool_s[r][e] = (red2[r][0][e] + red2[r][1][e] + red2[r][2][e] + red2[r][3][e])
                       * (1.f / 256.f);
    }
    __syncthreads();

    // node MLP layer 1: 8 rows x 64 hidden = 512 threads, 1 pass
    {
        const int r = j >> 6, u = j & 63;
        float s = nb1[u];
#pragma unroll
        for (int e = 0; e < 16; ++e)
            s = fmaf(pool_s[r][e], nW1[e * 64 + u], s);
        hid_s[r][u] = fmaxf(s, 0.f);
    }
    __syncthreads();

    // node MLP layer 2: 8 rows x 128 out = 1024 outputs, 2 passes
#pragma unroll
    for (int p = 0; p < 2; ++p) {
        const int idx = p * 512 + j;
        const int r = idx >> 7, o = idx & 127;
        float s = nb2[o];
#pragma unroll 8
        for (int q = 0; q < 64; ++q)
            s = fmaf(hid_s[r][q], nW2[q * 128 + o], s);
        msg_out[(size_t)(row0 + r) * 128 + o] = s;
    }
}

extern "C" void kernel_launch(void* const* d_in, const int* in_sizes, int n_in,
                              void* d_out, int out_size, void* d_ws, size_t ws_size,
                              hipStream_t stream)
{
    const float* node    = (const float*)d_in[0];
    const float* dist    = (const float*)d_in[1];
    const int*   visited = (const int*)  d_in[2];
    const float* dW1     = (const float*)d_in[3];
    const float* db1     = (const float*)d_in[4];
    const float* dW2     = (const float*)d_in[5];
    const float* db2     = (const float*)d_in[6];
    const float* uW1     = (const float*)d_in[7];
    const float* ub1     = (const float*)d_in[8];
    const float* ln_g    = (const float*)d_in[9];
    const float* ln_b    = (const float*)d_in[10];
    const float* uW2     = (const float*)d_in[11];
    const float* ub2     = (const float*)d_in[12];
    const float* nW1     = (const float*)d_in[13];
    const float* nb1     = (const float*)d_in[14];
    const float* nW2     = (const float*)d_in[15];
    const float* nb2     = (const float*)d_in[16];

    float* ws   = (float*)d_ws;
    float* bps  = ws;                    // 16
    float* albe = ws + 16;               // 1280 (1156 used + pad)
    float* Pi   = ws + 16 + 1280;        // 4096*32
    float* Pj   = Pi + 4096 * 32;        // 4096*32

    float* out = (float*)d_out;
    float* msg = out + EF_ELEMS;

    hipLaunchKernelGGL(k_prep_proj2, dim3(2049), dim3(256), 0, stream,
                       node, uW1, dW1, db1, dW2, db2, ub1, bps, albe, Pi, Pj);
    hipLaunchKernelGGL(k_edge9, dim3(512), dim3(512), 0, stream,
                       dist, visited, ln_g, ln_b, uW2, ub2, bps, albe, Pi, Pj,
                       nW1, nb1, nW2, nb2, out, msg);
}